// Round 9
// baseline (686.914 us; speedup 1.0000x reference)
//
#include <hip/hip_runtime.h>
#include <hip/hip_bf16.h>

// ---------------- problem constants ----------------
#define S_LEN  256
#define BATCH  32
#define SB     8192        // S*B
#define EDIM   512
#define HDIM   2000
#define HP     2048        // H padded to mult of 128
#define VDIM   10000
#define VP     10240       // V padded to mult of 128
#define EPS_BN 1e-5f

// M is BATCH-MAJOR everywhere: m' = b*256 + s. gather writes it, all GEMMs
// consume/produce it, the decoder de-permutes rows on store.

typedef __attribute__((ext_vector_type(8))) short bfx8;   // 8 x bf16 (4 VGPRs)
typedef __attribute__((ext_vector_type(4))) float f32x4;

__device__ __forceinline__ void gload_lds16(const void* g, void* l) {
  __builtin_amdgcn_global_load_lds(
      (const __attribute__((address_space(1))) void*)g,
      (__attribute__((address_space(3))) void*)l, 16, 0, 0);
}

__device__ __forceinline__ float bf_lo(unsigned int w) {
  return __builtin_bit_cast(float, (unsigned int)(w << 16));
}
__device__ __forceinline__ float bf_hi(unsigned int w) {
  return __builtin_bit_cast(float, (unsigned int)(w & 0xFFFF0000u));
}
__device__ __forceinline__ unsigned int bf_pack(float lo, float hi) {
  unsigned short a = __builtin_bit_cast(unsigned short, __float2bfloat16(lo));
  unsigned short b = __builtin_bit_cast(unsigned short, __float2bfloat16(hi));
  return (unsigned int)a | ((unsigned int)b << 16);
}

// ======== merged prep: 4 weight transposes + BN-fold params + gather ========
#define PREP_GRID 29788
__global__ __launch_bounds__(256) void prep_kernel(
    const float* __restrict__ W0, const float* __restrict__ Wr,
    const float* __restrict__ Wl, const float* __restrict__ Wd,
    __hip_bfloat16* __restrict__ wt0, __hip_bfloat16* __restrict__ wtr,
    __hip_bfloat16* __restrict__ wtl, __hip_bfloat16* __restrict__ wtd,
    const float* __restrict__ b0, const float* __restrict__ br,
    const float* __restrict__ g,  const float* __restrict__ be,
    const float* __restrict__ mu, const float* __restrict__ var,
    const float* __restrict__ bl, const float* __restrict__ gl,
    const float* __restrict__ bel,const float* __restrict__ mul_,
    const float* __restrict__ varl,
    const float* __restrict__ g2, const float* __restrict__ be2,
    const float* __restrict__ mu2,const float* __restrict__ var2,
    const float* __restrict__ bd,
    float* es, float* eh, float* fs, float* fh,
    float* s2, float* h2, float* ds, float* dh,
    const int* __restrict__ tokens, const float* __restrict__ emb,
    __hip_bfloat16* __restrict__ xb) {
  __shared__ float tile[32][33];
  const int id = blockIdx.x;
  const int t = threadIdx.x;

  if (id < 27648) {
    const float* W; __hip_bfloat16* Wt; int K, N, Kp, Np, bx, by;
    if (id < 1024) {
      W = W0; Wt = wt0; K = EDIM; N = HDIM; Kp = EDIM; Np = HP;
      bx = id & 15; by = id >> 4;
    } else if (id < 21504) {
      int rel = id - 1024; int l = rel >> 12; int r2 = rel & 4095;
      W = Wr + (size_t)l * HDIM * HDIM; Wt = wtr + (size_t)l * HP * HP;
      K = HDIM; N = HDIM; Kp = HP; Np = HP;
      bx = r2 & 63; by = r2 >> 6;
    } else if (id < 22528) {
      int rel = id - 21504;
      W = Wl; Wt = wtl; K = HDIM; N = EDIM; Kp = HP; Np = EDIM;
      bx = rel & 63; by = rel >> 6;
    } else {
      int rel = id - 22528;
      W = Wd; Wt = wtd; K = EDIM; N = VDIM; Kp = EDIM; Np = VP;
      bx = rel & 15; by = rel >> 4;
    }
    const int tx = t & 31, ty = t >> 5;
    const int kb = bx * 32, nb = by * 32;
#pragma unroll
    for (int i = 0; i < 4; i++) {
      int k = kb + ty + i * 8, n = nb + tx;
      tile[ty + i * 8][tx] = (k < K && n < N) ? W[(size_t)k * N + n] : 0.f;
    }
    __syncthreads();
#pragma unroll
    for (int i = 0; i < 4; i++) {
      int n = nb + ty + i * 8, k = kb + tx;
      if (n < Np && k < Kp) Wt[(size_t)n * Kp + k] = __float2bfloat16(tile[tx][ty + i * 8]);
    }
    return;
  }

  if (id < 27740) {
    int tt = (id - 27648) * 256 + t;
    if (tt < 6 * HP) {
      int l = tt >> 11, h = tt & (HP - 1);
      float sc = 0.f, sh = 0.f;
      if (h < HDIM) {
        float s = g[l * HDIM + h] * rsqrtf(var[l * HDIM + h] + EPS_BN);
        float bias = (l == 0) ? b0[h] : br[(l - 1) * HDIM + h];
        sc = s;
        sh = (bias - mu[l * HDIM + h]) * s + be[l * HDIM + h];
      }
      es[tt] = sc; eh[tt] = sh;
      return;
    }
    tt -= 6 * HP;
    if (tt < EDIM) {
      float s = gl[tt] * rsqrtf(varl[tt] + EPS_BN);
      fs[tt] = s; fh[tt] = (bl[tt] - mul_[tt]) * s + bel[tt];
      return;
    }
    tt -= EDIM;
    if (tt < EDIM) {
      float s = g2[tt] * rsqrtf(var2[tt] + EPS_BN);
      s2[tt] = s; h2[tt] = be2[tt] - mu2[tt] * s;
      return;
    }
    tt -= EDIM;
    if (tt < VP) {
      ds[tt] = 1.f; dh[tt] = (tt < VDIM) ? bd[tt] : 0.f;
    }
    return;
  }

  {
    int idx = (id - 27740) * 256 + t;       // SB*EDIM/8 threads
    int mprime = idx >> 6;                  // b*256 + s
    int e0 = (idx & 63) << 3;
    int s = mprime & 255, b = mprime >> 8;
    int tok = tokens[s * BATCH + b];
    const float* src = emb + (size_t)tok * EDIM + e0;
    float4 v0 = ((const float4*)src)[0];
    float4 v1 = ((const float4*)src)[1];
    __hip_bfloat16 tmp[8];
    tmp[0] = __float2bfloat16(v0.x); tmp[1] = __float2bfloat16(v0.y);
    tmp[2] = __float2bfloat16(v0.z); tmp[3] = __float2bfloat16(v0.w);
    tmp[4] = __float2bfloat16(v1.x); tmp[5] = __float2bfloat16(v1.y);
    tmp[6] = __float2bfloat16(v1.z); tmp[7] = __float2bfloat16(v1.w);
    *(bfx8*)&xb[(size_t)mprime * EDIM + e0] = *(const bfx8*)tmp;
  }
}

// ======== 256x256 GEMM, BK=32, 3-buffer ring, 4 phases/tile, vmcnt(4) ========
// Same barrier/MFMA-per-K cadence as the verified BK=64 8-phase schedule, but:
// one stage issue per wave per phase (uniform), one counted vmcnt per tile,
// 2-tile prefetch depth. FP accumulation order identical to R8 (canary: 8.0).
// LDS 96 KiB: A 3x16K @0, B 3x16K @49152. Layout: addr = buf*16384 + r*64 +
// ((c ^ (r&3))<<4)  (slot-XOR; inverse applied on global source, rule 21).
// Ledger: stage target buf (t+2)%3 == buf (t-1)%3, last read at t-1.ph2, two
// barriers before stage issue at t.ph0 -> safe. vmcnt(4) at t.ph3 retires
// exactly tile t+1's 4 loads (induction: 4 in flight at each tile start).
#define BARX  __builtin_amdgcn_s_barrier()
#define SP1   __builtin_amdgcn_s_setprio(1)
#define SP0   __builtin_amdgcn_s_setprio(0)
#define LGKM0 do { asm volatile("s_waitcnt lgkmcnt(0)" ::: "memory"); \
                   __builtin_amdgcn_sched_barrier(0); } while (0)
#define VMC(n) asm volatile("s_waitcnt vmcnt(" #n ")" ::: "memory")

__global__ __launch_bounds__(512, 2) void gemm256p_bf16_kernel(
    const __hip_bfloat16* __restrict__ A, int lda,
    const __hip_bfloat16* __restrict__ Bt, int ldb,
    __hip_bfloat16* __restrict__ Cb, float* __restrict__ Cf, int ldc,
    const float* __restrict__ epS, const float* __restrict__ epH,
    const float* __restrict__ uscan,
    int Kp, int Nstore, int grid_m, int chunk2d) {
  __shared__ __align__(16) char smem[98304];
  const int t = threadIdx.x, lane = t & 63, wid = t >> 6;
  const int nwg = gridDim.x, q = nwg >> 3, wg = blockIdx.x;
  int bm, bn;
  if (chunk2d) {                    // grid must be 32bm x 8bn (nwg==256)
    const int xc = wg & 7, i = wg >> 3;
    bm = xc * 4 + (i >> 3);         // 4 bm panels per XCD (A-chunk in L2)
    bn = i & 7;
  } else {
    const int swzb = (wg & 7) * q + (wg >> 3);   // bijective: nwg % 8 == 0
    bm = swzb % grid_m; bn = swzb / grid_m;
  }
  const int m0 = bm * 256, n0 = bn * 256;
  const int wm = wid >> 2, wn = wid & 3;

  // ---- staging constants: 1 gload_lds per wave per (tile, region) ----
  // issue covers 16 rows x 32 k: lane -> row = wid*16 + (lane>>2),
  // chunk c = (lane&3) ^ (row&3)  (inverse slot-XOR on global source)
  const int srow = lane >> 2;
  const int sch  = ((lane & 3) ^ (srow & 3)) * 8;
  const __hip_bfloat16* gA2 = A  + (size_t)(m0 + wid * 16 + srow) * lda + sch;
  const __hip_bfloat16* gB2 = Bt + (size_t)(n0 + wid * 16 + srow) * ldb + sch;
  char* const ldsA = (char*)smem;
  char* const ldsB = (char*)smem + 49152;

#define STA32(buf, e, kt) \
  gload_lds16(gA2 + (size_t)(e) * 128 * lda + (kt) * 32, \
              ldsA + (buf) * 16384 + (e) * 8192 + wid * 1024)
#define STB32(buf, o, kt) \
  gload_lds16(gB2 + (size_t)(o) * 128 * ldb + (kt) * 32, \
              ldsB + (buf) * 16384 + (o) * 8192 + wid * 1024)

  // ---- fragment reads (swizzled): row r -> r*64 + ((cc^(r&3))<<4) ----
  const int fr = lane & 15, cc = lane >> 4;
  const int xo = (cc ^ (fr & 3)) << 4;
  const char* rA32 = (char*)smem + (wm * 128 + fr) * 64 + xo;
  const char* rB32 = (char*)smem + 49152 + wn * 4096 + fr * 64 + xo;

#define RDA32(dst, bb, qa) do {                                               \
    _Pragma("unroll") for (int mi = 0; mi < 4; mi++)                          \
      dst[mi] = *(const bfx8*)(rA32 + (bb) * 16384 + (qa) * 4096 + mi * 1024);\
  } while (0)
#define RDB32(dst, bb, qb) do {                                               \
    _Pragma("unroll") for (int nf = 0; nf < 2; nf++)                          \
      dst[nf] = *(const bfx8*)(rB32 + (bb) * 16384 + (qb) * 2048 + nf * 1024);\
  } while (0)
#define MM32(qa, qb, aa, bb) do {                                             \
    _Pragma("unroll") for (int mi = 0; mi < 4; mi++)                          \
    _Pragma("unroll") for (int nf = 0; nf < 2; nf++)                          \
      acc[(qa) * 4 + mi][(qb) * 2 + nf] =                                     \
          __builtin_amdgcn_mfma_f32_16x16x32_bf16(                            \
              aa[mi], bb[nf], acc[(qa) * 4 + mi][(qb) * 2 + nf], 0, 0, 0);    \
  } while (0)

  // 4 phases per K-tile; DOSTAGE is a compile-time bool per instantiation.
#define TILE32(bt, st, kt2, DOSTAGE, ENDWAIT) do {                            \
    RDA32(a, bt, 0); RDB32(b0, bt, 0); if (DOSTAGE) STA32(st, 0, kt2);        \
    BARX; LGKM0; SP1; MM32(0, 0, a, b0); SP0; BARX;                           \
    RDB32(b2, bt, 1); if (DOSTAGE) STB32(st, 0, kt2);                         \
    BARX; LGKM0; SP1; MM32(0, 1, a, b2); SP0; BARX;                           \
    RDA32(a, bt, 1); if (DOSTAGE) STA32(st, 1, kt2);                          \
    BARX; LGKM0; SP1; MM32(1, 0, a, b0); SP0; BARX;                           \
    if (DOSTAGE) STB32(st, 1, kt2);                                           \
    BARX; LGKM0; SP1; MM32(1, 1, a, b2); SP0; ENDWAIT; BARX;                  \
  } while (0)

  f32x4 acc[8][4];
#pragma unroll
  for (int i = 0; i < 8; i++)
#pragma unroll
    for (int j = 0; j < 4; j++) acc[i][j] = (f32x4){0.f, 0.f, 0.f, 0.f};

  const int NT = Kp >> 5;          // K-tiles of 32 (NT >= 3 for all uses)

  // prologue: stage tiles 0 and 1 (4 loads each); retire tile 0's
  STA32(0, 0, 0); STB32(0, 0, 0); STA32(0, 1, 0); STB32(0, 1, 0);
  STA32(1, 0, 1); STB32(1, 0, 1); STA32(1, 1, 1); STB32(1, 1, 1);
  VMC(4); BARX;

  bfx8 a[4], b0[2], b2[2];
  int bt = 0;
  for (int kt = 0; kt < NT - 2; ++kt) {
    int st = bt + 2; if (st >= 3) st -= 3;
    TILE32(bt, st, kt + 2, true, VMC(4));
    bt = (bt + 1 == 3) ? 0 : bt + 1;
  }
  {  // tile NT-2: no stage; retire tile NT-1's loads
    TILE32(bt, 0, 0, false, VMC(0));
    bt = (bt + 1 == 3) ? 0 : bt + 1;
  }
  {  // tile NT-1: no stage, no wait
    TILE32(bt, 0, 0, false, (void)0);
  }
  // All vm-loads retired (VMC(0) above, no stages after); all ds_reads done
  // (LGKM0 before each MFMA + final barrier) -> LDS reusable.

  const int colb = n0 + wn * 64 + fr;
  const int rowb = wm * 128 + cc * 4;            // local row (= s, batch-major)

  if (uscan) {
    // ---- fused scan epilogue, two halves (region [128][256] bf16 = 64 KiB,
    //      fits the 96 KiB allocation). wm=0 waves hold s=0..127, wm=1 hold
    //      s=128..255; scan threads (t<256, all in wm=0 waves) keep running h
    //      in registers across the two fills. Bank-XOR as before.
    unsigned short* lds16 = (unsigned short*)smem;
    const int colL0 = wn * 64 + fr;
    if (wm == 0) {
#pragma unroll
      for (int nf = 0; nf < 4; nf++) {
        int colL = colL0 + nf * 16;
        float sc = epS[n0 + colL], sh = epH[n0 + colL];
#pragma unroll
        for (int mf = 0; mf < 8; mf++)
#pragma unroll
          for (int rr = 0; rr < 4; rr++) {
            int s = cc * 4 + mf * 16 + rr;       // 0..127
            int byte = ((s << 9) + (colL << 1)) ^ (((s >> 2) & 3) << 5);
            lds16[byte >> 1] = __builtin_bit_cast(unsigned short,
                __float2bfloat16(acc[mf][nf][rr] * sc + sh));
          }
      }
    }
    __syncthreads();
    float hrun = 0.f, uu = 0.f;
    __hip_bfloat16* xcol = nullptr;
    const int c = t;
    if (t < 256) {
      uu = (n0 + c < HDIM) ? uscan[n0 + c] : 0.f;
      xcol = Cb + (size_t)m0 * ldc + n0 + c;
      for (int s8 = 0; s8 < 128; s8 += 8) {
        unsigned short vv[8];
#pragma unroll
        for (int j = 0; j < 8; j++) {
          int s = s8 + j;
          int byte = ((s << 9) + (c << 1)) ^ (((s >> 2) & 3) << 5);
          vv[j] = lds16[byte >> 1];
        }
#pragma unroll
        for (int j = 0; j < 8; j++) {
          hrun = fmaxf(fmaf(uu, hrun, bf_lo((unsigned int)vv[j])), 0.f);
          xcol[(size_t)(s8 + j) * ldc] = __float2bfloat16(hrun);
        }
      }
    }
    __syncthreads();
    if (wm == 1) {
#pragma unroll
      for (int nf = 0; nf < 4; nf++) {
        int colL = colL0 + nf * 16;
        float sc = epS[n0 + colL], sh = epH[n0 + colL];
#pragma unroll
        for (int mf = 0; mf < 8; mf++)
#pragma unroll
          for (int rr = 0; rr < 4; rr++) {
            int s = cc * 4 + mf * 16 + rr;       // local; global = s+128
            int byte = ((s << 9) + (colL << 1)) ^ (((s >> 2) & 3) << 5);
            lds16[byte >> 1] = __builtin_bit_cast(unsigned short,
                __float2bfloat16(acc[mf][nf][rr] * sc + sh));
          }
      }
    }
    __syncthreads();
    if (t < 256) {
      for (int s8 = 0; s8 < 128; s8 += 8) {
        unsigned short vv[8];
#pragma unroll
        for (int j = 0; j < 8; j++) {
          int s = s8 + j;
          int byte = ((s << 9) + (c << 1)) ^ (((s >> 2) & 3) << 5);
          vv[j] = lds16[byte >> 1];
        }
#pragma unroll
        for (int j = 0; j < 8; j++) {
          hrun = fmaxf(fmaf(uu, hrun, bf_lo((unsigned int)vv[j])), 0.f);
          xcol[(size_t)(128 + s8 + j) * ldc] = __float2bfloat16(hrun);
        }
      }
    }
    return;
  }

#pragma unroll
  for (int nf = 0; nf < 4; nf++) {
    int col = colb + nf * 16;
    if (col >= Nstore) continue;
    float sc = epS[col], sh = epH[col];
    if (Cf) {
#pragma unroll
      for (int mf = 0; mf < 8; mf++)
#pragma unroll
        for (int rr = 0; rr < 4; rr++) {
          int s = rowb + mf * 16 + rr;
          Cf[(size_t)(s * BATCH + bm) * ldc + col] = acc[mf][nf][rr] * sc + sh;
        }
    } else {
#pragma unroll
      for (int mf = 0; mf < 8; mf++)
#pragma unroll
        for (int rr = 0; rr < 4; rr++)
          Cb[(size_t)(m0 + rowb + mf * 16 + rr) * ldc + col] =
              __float2bfloat16(acc[mf][nf][rr] * sc + sh);
    }
  }
}

// ---------------- 128x128 m97-structure GEMM (last_fc), bf16 out ----
__global__ __launch_bounds__(256, 2) void gemm128_bf16_kernel(
    const __hip_bfloat16* __restrict__ A, int lda,
    const __hip_bfloat16* __restrict__ Bt, int ldb,
    __hip_bfloat16* __restrict__ C, int ldc,
    const float* __restrict__ epS, const float* __restrict__ epH,
    int Kp, int Nstore) {
  __shared__ __align__(16) __hip_bfloat16 As[128 * 32];
  __shared__ __align__(16) __hip_bfloat16 Bs[128 * 32];
  const int t = threadIdx.x;
  const int lane = t & 63;
  const int wave = t >> 6;
  const int m0 = blockIdx.x * 128;
  const int n0 = blockIdx.y * 128;
  const int wm = (wave >> 1) * 64;
  const int wn = (wave & 1) * 64;

  f32x4 acc[4][4];
#pragma unroll
  for (int i = 0; i < 4; i++)
#pragma unroll
    for (int j = 0; j < 4; j++) acc[i][j] = (f32x4){0.f, 0.f, 0.f, 0.f};

  const int kc = (t & 3) * 8;
  for (int k0 = 0; k0 < Kp; k0 += 32) {
#pragma unroll
    for (int r = 0; r < 2; r++) {
      int row = (r * 256 + t) >> 2;
      gload_lds16(A  + (size_t)(m0 + row) * lda + k0 + kc, &As[(r * 256 + (wave << 6)) * 8]);
      gload_lds16(Bt + (size_t)(n0 + row) * ldb + k0 + kc, &Bs[(r * 256 + (wave << 6)) * 8]);
    }
    __syncthreads();

    bfx8 af[4], bfr[4];
    const int fr = lane & 15;
    const int ko = (lane >> 4) * 8;
#pragma unroll
    for (int f = 0; f < 4; f++) af[f]  = *(const bfx8*)&As[(wm + f * 16 + fr) * 32 + ko];
#pragma unroll
    for (int f = 0; f < 4; f++) bfr[f] = *(const bfx8*)&Bs[(wn + f * 16 + fr) * 32 + ko];
#pragma unroll
    for (int i = 0; i < 4; i++)
#pragma unroll
      for (int j = 0; j < 4; j++)
        acc[i][j] = __builtin_amdgcn_mfma_f32_16x16x32_bf16(af[i], bfr[j], acc[i][j], 0, 0, 0);
    __syncthreads();
  }

  const int colb = n0 + wn + (lane & 15);
  const int rowb = m0 + wm + ((lane >> 4) << 2);
#pragma unroll
  for (int j = 0; j < 4; j++) {
    int col = colb + j * 16;
    if (col >= Nstore) continue;
    float sc = epS[col], sh = epH[col];
#pragma unroll
    for (int i = 0; i < 4; i++)
#pragma unroll
      for (int r = 0; r < 4; r++)
        C[(size_t)(rowb + i * 16 + r) * ldc + col] =
            __float2bfloat16(acc[i][j][r] * sc + sh);
  }
}

// ------- final IndRNN scan (width EDIM) + extra BN, batch-major rows ---------
__global__ __launch_bounds__(64) void scan_final_kernel(
    const __hip_bfloat16* __restrict__ y, const float* __restrict__ ul,
    const float* __restrict__ s2, const float* __restrict__ h2,
    __hip_bfloat16* __restrict__ xb) {
  const int t = blockIdx.x * 64 + threadIdx.x;   // B * EDIM/2 threads
  const int e2 = t & (EDIM / 2 - 1);
  const int b  = t >> 8;                          // EDIM/2 == 256
  const int e0 = e2 * 2;
  const float u0 = ul[e0], u1 = ul[e0 + 1];
  const float sc0 = s2[e0], sh0 = h2[e0], sc1 = s2[e0 + 1], sh1 = h2[e0 + 1];
  const unsigned int* yp = (const unsigned int*)y;
  unsigned int* xp = (unsigned int*)xb;
  const size_t base0 = (size_t)b * 256 * (EDIM / 2) + e2;
  const size_t stride = EDIM / 2;
  float hv0 = 0.f, hv1 = 0.f;
  unsigned int q0[8], q1[8], q2[8], q3[8];
#define LD8(Q, bi) do { size_t o = base0 + (size_t)(bi) * 8 * stride;           \
    _Pragma("unroll") for (int j = 0; j < 8; j++) Q[j] = yp[o + (size_t)j * stride]; \
  } while (0)
#define PR8(Q, bi) do { size_t o = base0 + (size_t)(bi) * 8 * stride;           \
    _Pragma("unroll") for (int j = 0; j < 8; j++) {                             \
      hv0 = fmaxf(fmaf(u0, hv0, bf_lo(Q[j])), 0.f);                             \
      hv1 = fmaxf(fmaf(u1, hv1, bf_hi(Q[j])), 0.f);                             \
      xp[o + (size_t)j * stride] = bf_pack(hv0 * sc0 + sh0, hv1 * sc1 + sh1); } \
  } while (0)
  LD8(q0, 0); LD8(q1, 1); LD8(q2, 2);
  for (int c = 0; c < 32; c += 4) {
    LD8(q3, c + 3);
    PR8(q0, c);
    if (c + 4 < 32) LD8(q0, c + 4);
    PR8(q1, c + 1);
    if (c + 5 < 32) LD8(q1, c + 5);
    PR8(q2, c + 2);
    if (c + 6 < 32) LD8(q2, c + 6);
    PR8(q3, c + 3);
  }
#undef LD8
#undef PR8
}

// ---------------- launch ----------------
extern "C" void kernel_launch(void* const* d_in, const int* in_sizes, int n_in,
                              void* d_out, int out_size, void* d_ws, size_t ws_size,
                              hipStream_t stream) {
  const int*   tokens = (const int*)d_in[0];
  const float* emb  = (const float*)d_in[1];
  const float* W0   = (const float*)d_in[2];
  const float* b0   = (const float*)d_in[3];
  const float* Wr   = (const float*)d_in[4];
  const float* br   = (const float*)d_in[5];
  const float* u    = (const float*)d_in[6];
  const float* g    = (const float*)d_in[7];
  const float* be   = (const float*)d_in[8];
  const float* mu   = (const float*)d_in[9];
  const float* var  = (const float*)d_in[10];
  const float* Wl   = (const float*)d_in[11];
  const float* bl   = (const float*)d_in[12];
  const float* ul   = (const float*)d_in[13];
  const float* gl   = (const float*)d_in[14];
  const float* bel  = (const float*)d_in[15];
  const float* mul_ = (const float*)d_in[16];
  const float* varl = (const float*)d_in[17];
  const float* g2   = (const float*)d_in[18];
  const float* be2  = (const float*)d_in[19];
  const float* mu2  = (const float*)d_in[20];
  const float* var2 = (const float*)d_in[21];
  const float* Wd   = (const float*)d_in[22];
  const float* bd   = (const float*)d_in[23];
  float* out = (float*)d_out;

  char* w = (char*)d_ws;
  auto carve = [&](size_t bytes) { void* p = (void*)w; w += (bytes + 255) & ~(size_t)255; return p; };
  __hip_bfloat16* wt0 = (__hip_bfloat16*)carve((size_t)HP * EDIM * 2);
  __hip_bfloat16* wtr = (__hip_bfloat16*)carve((size_t)5 * HP * HP * 2);
  __hip_bfloat16* wtl = (__hip_bfloat16*)carve((size_t)EDIM * HP * 2);
  __hip_bfloat16* wtd = (__hip_bfloat16*)carve((size_t)VP * EDIM * 2);
  __hip_bfloat16* xb  = (__hip_bfloat16*)carve((size_t)SB * HP * 2);
  __hip_bfloat16* xb2 = (__hip_bfloat16*)carve((size_t)SB * HP * 2);
  __hip_bfloat16* yb  = (__hip_bfloat16*)carve((size_t)SB * EDIM * 2);
  float* es  = (float*)carve((size_t)6 * HP * 4);
  float* eh  = (float*)carve((size_t)6 * HP * 4);
  float* fs  = (float*)carve((size_t)EDIM * 4);
  float* fh  = (float*)carve((size_t)EDIM * 4);
  float* s2b = (float*)carve((size_t)EDIM * 4);
  float* h2b = (float*)carve((size_t)EDIM * 4);
  float* dsb = (float*)carve((size_t)VP * 4);
  float* dhb = (float*)carve((size_t)VP * 4);

  // merged prep: all transposes + BN-fold + gather in one launch
  prep_kernel<<<PREP_GRID, 256, 0, stream>>>(
      W0, Wr, Wl, Wd, wt0, wtr, wtl, wtd,
      b0, br, g, be, mu, var, bl, gl, bel, mul_, varl,
      g2, be2, mu2, var2, bd,
      es, eh, fs, fh, s2b, h2b, dsb, dhb,
      tokens, emb, xb);

  // layers 0..5: fused GEMM+BN+scan, ping-pong xb <-> xb2 (2D XCD chunking)
  __hip_bfloat16* src = xb;
  __hip_bfloat16* dst = xb2;
  gemm256p_bf16_kernel<<<(SB / 256) * (HP / 256), 512, 0, stream>>>(
      src, EDIM, wt0, EDIM, dst, nullptr, HP, es, eh, u, EDIM, HP, SB / 256, 1);
  { __hip_bfloat16* tmp = src; src = dst; dst = tmp; }
  for (int l = 1; l < 6; l++) {
    gemm256p_bf16_kernel<<<(SB / 256) * (HP / 256), 512, 0, stream>>>(
        src, HP, wtr + (size_t)(l - 1) * HP * HP, HP, dst, nullptr, HP,
        es + l * HP, eh + l * HP, u + (size_t)l * HDIM, HP, HP, SB / 256, 1);
    __hip_bfloat16* tmp = src; src = dst; dst = tmp;
  }

  // last_fc: [SB,HP] x [HP->EDIM] via 128^2 kernel, bf16 out (batch-major)
  gemm128_bf16_kernel<<<dim3(SB / 128, EDIM / 128), 256, 0, stream>>>(
      src, HP, wtl, HP, yb, EDIM, fs, fh, HP, EDIM);
  scan_final_kernel<<<BATCH * EDIM / 2 / 64, 64, 0, stream>>>(yb, ul, s2b, h2b, dst);

  // decoder: [SB,EDIM] x [EDIM->VP], f32 out with row de-permute (bn-chunk map)
  gemm256p_bf16_kernel<<<(SB / 256) * (VP / 256), 512, 0, stream>>>(
      dst, EDIM, wtd, EDIM, nullptr, out, VDIM, dsb, dhb, nullptr, EDIM, VDIM, SB / 256, 0);
}

// Round 10
// 600.442 us; speedup vs baseline: 1.1440x; 1.1440x over previous
//
#include <hip/hip_runtime.h>
#include <hip/hip_bf16.h>

// ---------------- problem constants ----------------
#define S_LEN  256
#define BATCH  32
#define SB     8192        // S*B
#define EDIM   512
#define HDIM   2000
#define HP     2048        // H padded to mult of 128
#define VDIM   10000
#define VP     10240       // V padded to mult of 128
#define EPS_BN 1e-5f

// M is BATCH-MAJOR everywhere: m' = b*256 + s. gather writes it, all GEMMs
// consume/produce it, the decoder de-permutes rows on store.
// R10 = exact revert to R8 (best measured: 597 us). R6 (32x32 MFMA) and
// R9 (BK=32 ring) both regressed -> BK=64/8-phase/16-MFMA-per-phase is the
// local optimum for this fused structure.

typedef __attribute__((ext_vector_type(8))) short bfx8;   // 8 x bf16 (4 VGPRs)
typedef __attribute__((ext_vector_type(4))) float f32x4;

__device__ __forceinline__ void gload_lds16(const void* g, void* l) {
  __builtin_amdgcn_global_load_lds(
      (const __attribute__((address_space(1))) void*)g,
      (__attribute__((address_space(3))) void*)l, 16, 0, 0);
}

__device__ __forceinline__ float bf_lo(unsigned int w) {
  return __builtin_bit_cast(float, (unsigned int)(w << 16));
}
__device__ __forceinline__ float bf_hi(unsigned int w) {
  return __builtin_bit_cast(float, (unsigned int)(w & 0xFFFF0000u));
}
__device__ __forceinline__ unsigned int bf_pack(float lo, float hi) {
  unsigned short a = __builtin_bit_cast(unsigned short, __float2bfloat16(lo));
  unsigned short b = __builtin_bit_cast(unsigned short, __float2bfloat16(hi));
  return (unsigned int)a | ((unsigned int)b << 16);
}

// ======== merged prep: 4 weight transposes + BN-fold params + gather ========
// blockIdx.x ranges:
//   [0,1024)        W0  transpose (16 x 64 tiles)
//   [1024,21504)    Wr  transpose (5 layers x 64x64 tiles)
//   [21504,22528)   Wl  transpose (64 x 16 tiles)
//   [22528,27648)   Wd  transpose (16 x 320 tiles)
//   [27648,27740)   ep_params (92 blocks x 256 = 23552 threads)
//   [27740,29788)   gather (2048 blocks)
#define PREP_GRID 29788
__global__ __launch_bounds__(256) void prep_kernel(
    const float* __restrict__ W0, const float* __restrict__ Wr,
    const float* __restrict__ Wl, const float* __restrict__ Wd,
    __hip_bfloat16* __restrict__ wt0, __hip_bfloat16* __restrict__ wtr,
    __hip_bfloat16* __restrict__ wtl, __hip_bfloat16* __restrict__ wtd,
    const float* __restrict__ b0, const float* __restrict__ br,
    const float* __restrict__ g,  const float* __restrict__ be,
    const float* __restrict__ mu, const float* __restrict__ var,
    const float* __restrict__ bl, const float* __restrict__ gl,
    const float* __restrict__ bel,const float* __restrict__ mul_,
    const float* __restrict__ varl,
    const float* __restrict__ g2, const float* __restrict__ be2,
    const float* __restrict__ mu2,const float* __restrict__ var2,
    const float* __restrict__ bd,
    float* es, float* eh, float* fs, float* fh,
    float* s2, float* h2, float* ds, float* dh,
    const int* __restrict__ tokens, const float* __restrict__ emb,
    __hip_bfloat16* __restrict__ xb) {
  __shared__ float tile[32][33];
  const int id = blockIdx.x;
  const int t = threadIdx.x;

  if (id < 27648) {
    const float* W; __hip_bfloat16* Wt; int K, N, Kp, Np, bx, by;
    if (id < 1024) {
      W = W0; Wt = wt0; K = EDIM; N = HDIM; Kp = EDIM; Np = HP;
      bx = id & 15; by = id >> 4;
    } else if (id < 21504) {
      int rel = id - 1024; int l = rel >> 12; int r2 = rel & 4095;
      W = Wr + (size_t)l * HDIM * HDIM; Wt = wtr + (size_t)l * HP * HP;
      K = HDIM; N = HDIM; Kp = HP; Np = HP;
      bx = r2 & 63; by = r2 >> 6;
    } else if (id < 22528) {
      int rel = id - 21504;
      W = Wl; Wt = wtl; K = HDIM; N = EDIM; Kp = HP; Np = EDIM;
      bx = rel & 63; by = rel >> 6;
    } else {
      int rel = id - 22528;
      W = Wd; Wt = wtd; K = EDIM; N = VDIM; Kp = EDIM; Np = VP;
      bx = rel & 15; by = rel >> 4;
    }
    const int tx = t & 31, ty = t >> 5;
    const int kb = bx * 32, nb = by * 32;
#pragma unroll
    for (int i = 0; i < 4; i++) {
      int k = kb + ty + i * 8, n = nb + tx;
      tile[ty + i * 8][tx] = (k < K && n < N) ? W[(size_t)k * N + n] : 0.f;
    }
    __syncthreads();
#pragma unroll
    for (int i = 0; i < 4; i++) {
      int n = nb + ty + i * 8, k = kb + tx;
      if (n < Np && k < Kp) Wt[(size_t)n * Kp + k] = __float2bfloat16(tile[tx][ty + i * 8]);
    }
    return;
  }

  if (id < 27740) {
    int tt = (id - 27648) * 256 + t;
    if (tt < 6 * HP) {
      int l = tt >> 11, h = tt & (HP - 1);
      float sc = 0.f, sh = 0.f;
      if (h < HDIM) {
        float s = g[l * HDIM + h] * rsqrtf(var[l * HDIM + h] + EPS_BN);
        float bias = (l == 0) ? b0[h] : br[(l - 1) * HDIM + h];
        sc = s;
        sh = (bias - mu[l * HDIM + h]) * s + be[l * HDIM + h];
      }
      es[tt] = sc; eh[tt] = sh;
      return;
    }
    tt -= 6 * HP;
    if (tt < EDIM) {
      float s = gl[tt] * rsqrtf(varl[tt] + EPS_BN);
      fs[tt] = s; fh[tt] = (bl[tt] - mul_[tt]) * s + bel[tt];
      return;
    }
    tt -= EDIM;
    if (tt < EDIM) {
      float s = g2[tt] * rsqrtf(var2[tt] + EPS_BN);
      s2[tt] = s; h2[tt] = be2[tt] - mu2[tt] * s;
      return;
    }
    tt -= EDIM;
    if (tt < VP) {
      ds[tt] = 1.f; dh[tt] = (tt < VDIM) ? bd[tt] : 0.f;
    }
    return;
  }

  {
    int idx = (id - 27740) * 256 + t;       // SB*EDIM/8 threads
    int mprime = idx >> 6;                  // b*256 + s
    int e0 = (idx & 63) << 3;
    int s = mprime & 255, b = mprime >> 8;
    int tok = tokens[s * BATCH + b];
    const float* src = emb + (size_t)tok * EDIM + e0;
    float4 v0 = ((const float4*)src)[0];
    float4 v1 = ((const float4*)src)[1];
    __hip_bfloat16 tmp[8];
    tmp[0] = __float2bfloat16(v0.x); tmp[1] = __float2bfloat16(v0.y);
    tmp[2] = __float2bfloat16(v0.z); tmp[3] = __float2bfloat16(v0.w);
    tmp[4] = __float2bfloat16(v1.x); tmp[5] = __float2bfloat16(v1.y);
    tmp[6] = __float2bfloat16(v1.z); tmp[7] = __float2bfloat16(v1.w);
    *(bfx8*)&xb[(size_t)mprime * EDIM + e0] = *(const bfx8*)tmp;
  }
}

// ======== 256x256 8-phase GEMM (BK=64, 2 LDS bufs, counted vmcnt(6)) =========
// Epilogues: uscan!=null -> fused block-local IndRNN scan (y->LDS->scan->Cb);
//            Cf!=null    -> f32 store with row de-permute (out row = s*32+bm);
//            else        -> plain bf16 store.
// Block mapping: chunk2d!=0 (requires grid 32x8): each XCD owns a 4bm x 8bn
//   sub-grid -> A-chunk (4 MB) stays in its L2; L3 traffic 96 MB vs 264 MB.
//   chunk2d==0: bn-chunk per XCD (B panels L2-resident; used for decoder).
#define BARX  __builtin_amdgcn_s_barrier()
#define SP1   __builtin_amdgcn_s_setprio(1)
#define SP0   __builtin_amdgcn_s_setprio(0)
#define LGKM0 do { asm volatile("s_waitcnt lgkmcnt(0)" ::: "memory"); \
                   __builtin_amdgcn_sched_barrier(0); } while (0)
#define VMC(n) asm volatile("s_waitcnt vmcnt(" #n ")" ::: "memory")

__global__ __launch_bounds__(512, 2) void gemm256p_bf16_kernel(
    const __hip_bfloat16* __restrict__ A, int lda,
    const __hip_bfloat16* __restrict__ Bt, int ldb,
    __hip_bfloat16* __restrict__ Cb, float* __restrict__ Cf, int ldc,
    const float* __restrict__ epS, const float* __restrict__ epH,
    const float* __restrict__ uscan,
    int Kp, int Nstore, int grid_m, int chunk2d) {
  __shared__ __align__(16) char smem[131072];
  const int t = threadIdx.x, lane = t & 63, wid = t >> 6;
  const int nwg = gridDim.x, q = nwg >> 3, wg = blockIdx.x;
  int bm, bn;
  if (chunk2d) {                    // grid must be 32bm x 8bn (nwg==256)
    const int xc = wg & 7, i = wg >> 3;
    bm = xc * 4 + (i >> 3);         // 4 bm panels per XCD (A-chunk in L2)
    bn = i & 7;                     // bn varies fastest within XCD
  } else {
    const int swzb = (wg & 7) * q + (wg >> 3);   // bijective: nwg % 8 == 0
    bm = swzb % grid_m; bn = swzb / grid_m;
  }
  const int m0 = bm * 256, n0 = bn * 256;
  const int wm = wid >> 2, wn = wid & 3;

  const int lrow = lane >> 3;
  const int lch  = ((lane & 7) ^ lrow) * 8;
  const __hip_bfloat16* gA = A  + (size_t)(m0 + wid * 8 + lrow) * lda + lch;
  const __hip_bfloat16* gB = Bt + (size_t)(n0 + (wid >> 2) * 64 + (wid & 3) * 8 + lrow) * ldb + lch;
  char* const ldsA = (char*)smem;
  char* const ldsB = (char*)smem + 65536;
  const int laoff = wid * 1024;
  const int lboff = (wid >> 2) * 8192 + (wid & 3) * 1024;

#define STA(buf, e, kt) do {                                                   \
    gload_lds16(gA + (size_t)((e) * 64) * lda + (kt) * 64,                     \
                ldsA + (buf) * 32768 + (e) * 8192 + laoff);                    \
    gload_lds16(gA + (size_t)(128 + (e) * 64) * lda + (kt) * 64,               \
                ldsA + (buf) * 32768 + 16384 + (e) * 8192 + laoff);            \
  } while (0)
#define STB(buf, o, kt) do {                                                   \
    gload_lds16(gB + (size_t)((o) * 32) * ldb + (kt) * 64,                     \
                ldsB + (buf) * 32768 + (o) * 4096 + lboff);                    \
    gload_lds16(gB + (size_t)(128 + (o) * 32) * ldb + (kt) * 64,               \
                ldsB + (buf) * 32768 + 16384 + (o) * 4096 + lboff);            \
  } while (0)

  const int fr = lane & 15, cc = lane >> 4;
  const int sz = (fr & 7) << 4;
  const int ak0 = (cc * 16) ^ sz;
  const int ak1 = (64 + cc * 16) ^ sz;
  const char* rA = (char*)smem + (wm * 128 + fr) * 128;
  const char* rB = (char*)smem + 65536 + (wn * 64 + fr) * 128;

#define RDA(dst, buf, qa) do {                                                 \
    _Pragma("unroll") for (int mi = 0; mi < 4; mi++) {                         \
      dst[mi][0] = *(const bfx8*)(rA + (buf) * 32768 + (qa) * 8192 + mi * 2048 + ak0); \
      dst[mi][1] = *(const bfx8*)(rA + (buf) * 32768 + (qa) * 8192 + mi * 2048 + ak1); \
    } } while (0)
#define RDB(dst, buf, qb) do {                                                 \
    _Pragma("unroll") for (int nf = 0; nf < 2; nf++) {                         \
      dst[nf][0] = *(const bfx8*)(rB + (buf) * 32768 + (qb) * 4096 + nf * 2048 + ak0); \
      dst[nf][1] = *(const bfx8*)(rB + (buf) * 32768 + (qb) * 4096 + nf * 2048 + ak1); \
    } } while (0)
#define MM(qa, qb, aa, bb) do {                                                \
    _Pragma("unroll") for (int mi = 0; mi < 4; mi++)                           \
    _Pragma("unroll") for (int nf = 0; nf < 2; nf++)                           \
    _Pragma("unroll") for (int kk = 0; kk < 2; kk++)                           \
      acc[(qa) * 4 + mi][(qb) * 2 + nf] = __builtin_amdgcn_mfma_f32_16x16x32_bf16( \
          aa[mi][kk], bb[nf][kk], acc[(qa) * 4 + mi][(qb) * 2 + nf], 0, 0, 0); \
  } while (0)

  f32x4 acc[8][4];
#pragma unroll
  for (int i = 0; i < 8; i++)
#pragma unroll
    for (int j = 0; j < 4; j++) acc[i][j] = (f32x4){0.f, 0.f, 0.f, 0.f};

  const int NT = Kp >> 6;
  const int NI = NT >> 1;

  STA(0, 0, 0); STB(0, 0, 0); STB(0, 1, 0); STA(0, 1, 0);
  STA(1, 0, 1); STB(1, 0, 1);
  VMC(4); BARX;

  bfx8 a[4][2], b0[2][2], b2[2][2];
  for (int it = 0; it < NI - 1; ++it) {
    const int kt1 = 2 * it + 1, t2 = 2 * it + 2, t3 = 2 * it + 3;
    RDA(a, 0, 0); RDB(b0, 0, 0); STB(1, 1, kt1);
    BARX; LGKM0; SP1; MM(0, 0, a, b0); SP0; BARX;
    RDB(b2, 0, 1); STA(1, 1, kt1);
    BARX; LGKM0; SP1; MM(0, 1, a, b2); SP0; VMC(6); BARX;
    RDA(a, 0, 1); STA(0, 0, t2);
    BARX; LGKM0; SP1; MM(1, 0, a, b0); SP0; BARX;
    STB(0, 0, t2);
    BARX; LGKM0; SP1; MM(1, 1, a, b2); SP0; VMC(6); BARX;
    RDA(a, 1, 0); RDB(b0, 1, 0); STB(0, 1, t2);
    BARX; LGKM0; SP1; MM(0, 0, a, b0); SP0; BARX;
    RDB(b2, 1, 1); STA(0, 1, t2);
    BARX; LGKM0; SP1; MM(0, 1, a, b2); SP0; VMC(6); BARX;
    RDA(a, 1, 1); STA(1, 0, t3);
    BARX; LGKM0; SP1; MM(1, 0, a, b0); SP0; BARX;
    STB(1, 0, t3);
    BARX; LGKM0; SP1; MM(1, 1, a, b2); SP0; VMC(6); BARX;
  }
  {
    const int kt1 = NT - 1;
    RDA(a, 0, 0); RDB(b0, 0, 0); STB(1, 1, kt1);
    BARX; LGKM0; SP1; MM(0, 0, a, b0); SP0; BARX;
    RDB(b2, 0, 1); STA(1, 1, kt1);
    BARX; LGKM0; SP1; MM(0, 1, a, b2); SP0; VMC(6); BARX;
    RDA(a, 0, 1);
    BARX; LGKM0; SP1; MM(1, 0, a, b0); SP0; BARX;
    BARX; LGKM0; SP1; MM(1, 1, a, b2); SP0; VMC(2); BARX;
    RDA(a, 1, 0); RDB(b0, 1, 0);
    BARX; LGKM0; SP1; MM(0, 0, a, b0); SP0; BARX;
    RDB(b2, 1, 1);
    BARX; LGKM0; SP1; MM(0, 1, a, b2); SP0; VMC(0); BARX;
    RDA(a, 1, 1);
    BARX; LGKM0; SP1; MM(1, 0, a, b0); SP0; BARX;
    BARX; LGKM0; SP1; MM(1, 1, a, b2); SP0; BARX;
  }
  VMC(0);
  // All vm-loads drained and all ds_reads complete -> LDS reusable.

  const int colb = n0 + wn * 64 + fr;
  const int rowb = wm * 128 + cc * 4;            // local row (= s, batch-major)

  if (uscan) {
    // ---- fused epilogue: y -> LDS [s=256][col=256] bf16 (bank-XOR), scan ----
    unsigned short* lds16 = (unsigned short*)smem;
    const int colL0 = wn * 64 + fr;
#pragma unroll
    for (int nf = 0; nf < 4; nf++) {
      int colL = colL0 + nf * 16;
      float sc = epS[n0 + colL], sh = epH[n0 + colL];
#pragma unroll
      for (int mf = 0; mf < 8; mf++) {
#pragma unroll
        for (int rr = 0; rr < 4; rr++) {
          int s = rowb + mf * 16 + rr;
          int byte = ((s << 9) + (colL << 1)) ^ (((s >> 2) & 3) << 5);
          lds16[byte >> 1] = __builtin_bit_cast(unsigned short,
              __float2bfloat16(acc[mf][nf][rr] * sc + sh));
        }
      }
    }
    __syncthreads();
    if (t < 256) {
      const int c = t;
      const float uu = (n0 + c < HDIM) ? uscan[n0 + c] : 0.f;
      float h = 0.f;
      __hip_bfloat16* xcol = Cb + (size_t)m0 * ldc + n0 + c;
      for (int s8 = 0; s8 < 256; s8 += 8) {
        unsigned short vv[8];
#pragma unroll
        for (int j = 0; j < 8; j++) {
          int s = s8 + j;
          int byte = ((s << 9) + (c << 1)) ^ (((s >> 2) & 3) << 5);
          vv[j] = lds16[byte >> 1];
        }
#pragma unroll
        for (int j = 0; j < 8; j++) {
          h = fmaxf(fmaf(uu, h, bf_lo((unsigned int)vv[j])), 0.f);
          xcol[(size_t)(s8 + j) * ldc] = __float2bfloat16(h);
        }
      }
    }
    return;
  }

#pragma unroll
  for (int nf = 0; nf < 4; nf++) {
    int col = colb + nf * 16;
    if (col >= Nstore) continue;
    float sc = epS[col], sh = epH[col];
    if (Cf) {
#pragma unroll
      for (int mf = 0; mf < 8; mf++)
#pragma unroll
        for (int rr = 0; rr < 4; rr++) {
          int s = rowb + mf * 16 + rr;
          Cf[(size_t)(s * BATCH + bm) * ldc + col] = acc[mf][nf][rr] * sc + sh;
        }
    } else {
#pragma unroll
      for (int mf = 0; mf < 8; mf++)
#pragma unroll
        for (int rr = 0; rr < 4; rr++)
          Cb[(size_t)(m0 + rowb + mf * 16 + rr) * ldc + col] =
              __float2bfloat16(acc[mf][nf][rr] * sc + sh);
    }
  }
}

// ---------------- 128x128 m97-structure GEMM (last_fc), bf16 out ----
__global__ __launch_bounds__(256, 2) void gemm128_bf16_kernel(
    const __hip_bfloat16* __restrict__ A, int lda,
    const __hip_bfloat16* __restrict__ Bt, int ldb,
    __hip_bfloat16* __restrict__ C, int ldc,
    const float* __restrict__ epS, const float* __restrict__ epH,
    int Kp, int Nstore) {
  __shared__ __align__(16) __hip_bfloat16 As[128 * 32];
  __shared__ __align__(16) __hip_bfloat16 Bs[128 * 32];
  const int t = threadIdx.x;
  const int lane = t & 63;
  const int wave = t >> 6;
  const int m0 = blockIdx.x * 128;
  const int n0 = blockIdx.y * 128;
  const int wm = (wave >> 1) * 64;
  const int wn = (wave & 1) * 64;

  f32x4 acc[4][4];
#pragma unroll
  for (int i = 0; i < 4; i++)
#pragma unroll
    for (int j = 0; j < 4; j++) acc[i][j] = (f32x4){0.f, 0.f, 0.f, 0.f};

  const int kc = (t & 3) * 8;
  for (int k0 = 0; k0 < Kp; k0 += 32) {
#pragma unroll
    for (int r = 0; r < 2; r++) {
      int row = (r * 256 + t) >> 2;
      gload_lds16(A  + (size_t)(m0 + row) * lda + k0 + kc, &As[(r * 256 + (wave << 6)) * 8]);
      gload_lds16(Bt + (size_t)(n0 + row) * ldb + k0 + kc, &Bs[(r * 256 + (wave << 6)) * 8]);
    }
    __syncthreads();

    bfx8 af[4], bfr[4];
    const int fr = lane & 15;
    const int ko = (lane >> 4) * 8;
#pragma unroll
    for (int f = 0; f < 4; f++) af[f]  = *(const bfx8*)&As[(wm + f * 16 + fr) * 32 + ko];
#pragma unroll
    for (int f = 0; f < 4; f++) bfr[f] = *(const bfx8*)&Bs[(wn + f * 16 + fr) * 32 + ko];
#pragma unroll
    for (int i = 0; i < 4; i++)
#pragma unroll
      for (int j = 0; j < 4; j++)
        acc[i][j] = __builtin_amdgcn_mfma_f32_16x16x32_bf16(af[i], bfr[j], acc[i][j], 0, 0, 0);
    __syncthreads();
  }

  const int colb = n0 + wn + (lane & 15);
  const int rowb = m0 + wm + ((lane >> 4) << 2);
#pragma unroll
  for (int j = 0; j < 4; j++) {
    int col = colb + j * 16;
    if (col >= Nstore) continue;
    float sc = epS[col], sh = epH[col];
#pragma unroll
    for (int i = 0; i < 4; i++)
#pragma unroll
      for (int r = 0; r < 4; r++)
        C[(size_t)(rowb + i * 16 + r) * ldc + col] =
            __float2bfloat16(acc[i][j][r] * sc + sh);
  }
}

// ------- final IndRNN scan (width EDIM) + extra BN, batch-major rows ---------
__global__ __launch_bounds__(64) void scan_final_kernel(
    const __hip_bfloat16* __restrict__ y, const float* __restrict__ ul,
    const float* __restrict__ s2, const float* __restrict__ h2,
    __hip_bfloat16* __restrict__ xb) {
  const int t = blockIdx.x * 64 + threadIdx.x;   // B * EDIM/2 threads
  const int e2 = t & (EDIM / 2 - 1);
  const int b  = t >> 8;                          // EDIM/2 == 256
  const int e0 = e2 * 2;
  const float u0 = ul[e0], u1 = ul[e0 + 1];
  const float sc0 = s2[e0], sh0 = h2[e0], sc1 = s2[e0 + 1], sh1 = h2[e0 + 1];
  const unsigned int* yp = (const unsigned int*)y;
  unsigned int* xp = (unsigned int*)xb;
  const size_t base0 = (size_t)b * 256 * (EDIM / 2) + e2;
  const size_t stride = EDIM / 2;
  float hv0 = 0.f, hv1 = 0.f;
  unsigned int q0[8], q1[8], q2[8], q3[8];
#define LD8(Q, bi) do { size_t o = base0 + (size_t)(bi) * 8 * stride;           \
    _Pragma("unroll") for (int j = 0; j < 8; j++) Q[j] = yp[o + (size_t)j * stride]; \
  } while (0)
#define PR8(Q, bi) do { size_t o = base0 + (size_t)(bi) * 8 * stride;           \
    _Pragma("unroll") for (int j = 0; j < 8; j++) {                             \
      hv0 = fmaxf(fmaf(u0, hv0, bf_lo(Q[j])), 0.f);                             \
      hv1 = fmaxf(fmaf(u1, hv1, bf_hi(Q[j])), 0.f);                             \
      xp[o + (size_t)j * stride] = bf_pack(hv0 * sc0 + sh0, hv1 * sc1 + sh1); } \
  } while (0)
  LD8(q0, 0); LD8(q1, 1); LD8(q2, 2);
  for (int c = 0; c < 32; c += 4) {
    LD8(q3, c + 3);
    PR8(q0, c);
    if (c + 4 < 32) LD8(q0, c + 4);
    PR8(q1, c + 1);
    if (c + 5 < 32) LD8(q1, c + 5);
    PR8(q2, c + 2);
    if (c + 6 < 32) LD8(q2, c + 6);
    PR8(q3, c + 3);
  }
#undef LD8
#undef PR8
}

// ---------------- launch ----------------
extern "C" void kernel_launch(void* const* d_in, const int* in_sizes, int n_in,
                              void* d_out, int out_size, void* d_ws, size_t ws_size,
                              hipStream_t stream) {
  const int*   tokens = (const int*)d_in[0];
  const float* emb  = (const float*)d_in[1];
  const float* W0   = (const float*)d_in[2];
  const float* b0   = (const float*)d_in[3];
  const float* Wr   = (const float*)d_in[4];
  const float* br   = (const float*)d_in[5];
  const float* u    = (const float*)d_in[6];
  const float* g    = (const float*)d_in[7];
  const float* be   = (const float*)d_in[8];
  const float* mu   = (const float*)d_in[9];
  const float* var  = (const float*)d_in[10];
  const float* Wl   = (const float*)d_in[11];
  const float* bl   = (const float*)d_in[12];
  const float* ul   = (const float*)d_in[13];
  const float* gl   = (const float*)d_in[14];
  const float* bel  = (const float*)d_in[15];
  const float* mul_ = (const float*)d_in[16];
  const float* varl = (const float*)d_in[17];
  const float* g2   = (const float*)d_in[18];
  const float* be2  = (const float*)d_in[19];
  const float* mu2  = (const float*)d_in[20];
  const float* var2 = (const float*)d_in[21];
  const float* Wd   = (const float*)d_in[22];
  const float* bd   = (const float*)d_in[23];
  float* out = (float*)d_out;

  char* w = (char*)d_ws;
  auto carve = [&](size_t bytes) { void* p = (void*)w; w += (bytes + 255) & ~(size_t)255; return p; };
  __hip_bfloat16* wt0 = (__hip_bfloat16*)carve((size_t)HP * EDIM * 2);
  __hip_bfloat16* wtr = (__hip_bfloat16*)carve((size_t)5 * HP * HP * 2);
  __hip_bfloat16* wtl = (__hip_bfloat16*)carve((size_t)EDIM * HP * 2);
  __hip_bfloat16* wtd = (__hip_bfloat16*)carve((size_t)VP * EDIM * 2);
  __hip_bfloat16* xb  = (__hip_bfloat16*)carve((size_t)SB * HP * 2);
  __hip_bfloat16* xb2 = (__hip_bfloat16*)carve((size_t)SB * HP * 2);
  __hip_bfloat16* yb  = (__hip_bfloat16*)carve((size_t)SB * EDIM * 2);
  float* es  = (float*)carve((size_t)6 * HP * 4);
  float* eh  = (float*)carve((size_t)6 * HP * 4);
  float* fs  = (float*)carve((size_t)EDIM * 4);
  float* fh  = (float*)carve((size_t)EDIM * 4);
  float* s2b = (float*)carve((size_t)EDIM * 4);
  float* h2b = (float*)carve((size_t)EDIM * 4);
  float* dsb = (float*)carve((size_t)VP * 4);
  float* dhb = (float*)carve((size_t)VP * 4);

  // merged prep: all transposes + BN-fold + gather in one launch
  prep_kernel<<<PREP_GRID, 256, 0, stream>>>(
      W0, Wr, Wl, Wd, wt0, wtr, wtl, wtd,
      b0, br, g, be, mu, var, bl, gl, bel, mul_, varl,
      g2, be2, mu2, var2, bd,
      es, eh, fs, fh, s2b, h2b, dsb, dhb,
      tokens, emb, xb);

  // layers 0..5: fused GEMM+BN+scan, ping-pong xb <-> xb2 (2D XCD chunking)
  __hip_bfloat16* src = xb;
  __hip_bfloat16* dst = xb2;
  gemm256p_bf16_kernel<<<(SB / 256) * (HP / 256), 512, 0, stream>>>(
      src, EDIM, wt0, EDIM, dst, nullptr, HP, es, eh, u, EDIM, HP, SB / 256, 1);
  { __hip_bfloat16* tmp = src; src = dst; dst = tmp; }
  for (int l = 1; l < 6; l++) {
    gemm256p_bf16_kernel<<<(SB / 256) * (HP / 256), 512, 0, stream>>>(
        src, HP, wtr + (size_t)(l - 1) * HP * HP, HP, dst, nullptr, HP,
        es + l * HP, eh + l * HP, u + (size_t)l * HDIM, HP, HP, SB / 256, 1);
    __hip_bfloat16* tmp = src; src = dst; dst = tmp;
  }

  // last_fc: [SB,HP] x [HP->EDIM] via 128^2 kernel, bf16 out (batch-major)
  gemm128_bf16_kernel<<<dim3(SB / 128, EDIM / 128), 256, 0, stream>>>(
      src, HP, wtl, HP, yb, EDIM, fs, fh, HP, EDIM);
  scan_final_kernel<<<BATCH * EDIM / 2 / 64, 64, 0, stream>>>(yb, ul, s2b, h2b, dst);

  // decoder: [SB,EDIM] x [EDIM->VP], f32 out with row de-permute (bn-chunk map)
  gemm256p_bf16_kernel<<<(SB / 256) * (VP / 256), 512, 0, stream>>>(
      dst, EDIM, wtd, EDIM, nullptr, out, VDIM, dsb, dhb, nullptr, EDIM, VDIM, SB / 256, 0);
}